// Round 1
// baseline (163.678 us; speedup 1.0000x reference)
//
#include <hip/hip_runtime.h>
#include <stdint.h>
#include <stddef.h>

#define BATCH 256
#define OC 4096
#define IC 4096
#define VALUE_SCALE 0.1f

#define BN 128          // N-tile (output features per WG)
#define BK 32           // K-step
#define KS 8            // split-K factor
#define KPER (IC / KS)  // 512
#define NT (KPER / BK)  // 16 K-steps

typedef float f32x4 __attribute__((ext_vector_type(4)));
typedef int   i32x4 __attribute__((ext_vector_type(4)));
typedef short bf16x8 __attribute__((ext_vector_type(8)));

__device__ __forceinline__ unsigned short f2bf(float f) {
    union { float f; uint32_t u; } c; c.f = f;
    uint32_t u = c.u;
    uint32_t r = u + 0x7FFFu + ((u >> 16) & 1u);   // RNE
    return (unsigned short)(r >> 16);
}
__device__ __forceinline__ float bf2f(unsigned short s) {
    union { uint32_t u; float f; } c; c.u = ((uint32_t)s) << 16;
    return c.f;
}

// ---------------- scatter: w[idx[i]] = val[i] * 0.1 (set; idempotent) ----------------
__global__ void scatter_k(float* __restrict__ w, const int* __restrict__ idx,
                          const float* __restrict__ val, int n) {
    int i = (blockIdx.x * blockDim.x + threadIdx.x) * 4;
    if (i + 4 <= n) {
        i32x4 id = *(const i32x4*)(idx + i);
        f32x4 v  = *(const f32x4*)(val + i);
        w[id[0]] = v[0] * VALUE_SCALE;
        w[id[1]] = v[1] * VALUE_SCALE;
        w[id[2]] = v[2] * VALUE_SCALE;
        w[id[3]] = v[3] * VALUE_SCALE;
    } else {
        for (int j = i; j < n; ++j) w[idx[j]] = val[j] * VALUE_SCALE;
    }
}

// ---------------- split-K bf16x3 GEMM: y[m,n] += sum_k x[m,k]*w[n,k] ----------------
// grid = 256: ks = bid&7 (XCD-pinned K-slice), bn = bid>>3 (N-tile).
// Block 256 thr = 4 waves; wave tile 64x128 = 4(m) x 8(n) frags of 16x16.
// LDS 96KB: double-buffered bf16 hi/lo tiles; fp32->bf16 split fused in staging.
__global__ __launch_bounds__(256, 1) void gemm_k(const float* __restrict__ x,
                                                 const float* __restrict__ w,
                                                 float* __restrict__ y) {
    const int tid  = threadIdx.x;
    const int lane = tid & 63;
    const int wv   = tid >> 6;          // wave 0..3 -> rows wv*64..+64
    const int bid  = blockIdx.x;
    const int ks   = bid & 7;
    const int bn   = bid >> 3;
    const int k0   = ks * KPER;
    const int nc0  = bn * BN;

    __shared__ __align__(16) short Ah[2][BATCH * BK];  // 32KB
    __shared__ __align__(16) short Al[2][BATCH * BK];  // 32KB
    __shared__ __align__(16) short Bh[2][BN * BK];     // 16KB
    __shared__ __align__(16) short Bl[2][BN * BK];     // 16KB

    f32x4 acc[4][8];
#pragma unroll
    for (int m = 0; m < 4; ++m)
#pragma unroll
        for (int n = 0; n < 8; ++n) acc[m][n] = (f32x4)0.0f;

    f32x4 ar[8];  // in-flight A tile (32 floats)
    f32x4 br[4];  // in-flight B tile (16 floats)

    // issue global loads for K-step t (kept in regs; consumed by stage_write)
    auto stage_load = [&](int t) {
        const int kg = k0 + t * BK;
#pragma unroll
        for (int p = 0; p < 4; ++p) {
            int id = tid + p * 256; int row = id >> 2; int slot = id & 3;
            const float* s = x + (size_t)row * IC + kg + slot * 8;
            ar[2 * p]     = *(const f32x4*)s;
            ar[2 * p + 1] = *(const f32x4*)(s + 4);
        }
#pragma unroll
        for (int p = 0; p < 2; ++p) {
            int id = tid + p * 256; int row = id >> 2; int slot = id & 3;
            const float* s = w + (size_t)(nc0 + row) * IC + kg + slot * 8;
            br[2 * p]     = *(const f32x4*)s;
            br[2 * p + 1] = *(const f32x4*)(s + 4);
        }
    };

    // convert fp32 -> bf16 hi/lo and write swizzled LDS tiles
    auto stage_write = [&](int buf) {
#pragma unroll
        for (int p = 0; p < 4; ++p) {
            int id = tid + p * 256; int row = id >> 2; int slotl = id & 3;
            int slot = slotl ^ ((row >> 1) & 3);
            bf16x8 hv, lv;
#pragma unroll
            for (int j = 0; j < 4; ++j) {
                float f0 = ar[2 * p][j];
                unsigned short h0 = f2bf(f0);
                hv[j] = (short)h0; lv[j] = (short)f2bf(f0 - bf2f(h0));
                float f1 = ar[2 * p + 1][j];
                unsigned short h1 = f2bf(f1);
                hv[j + 4] = (short)h1; lv[j + 4] = (short)f2bf(f1 - bf2f(h1));
            }
            *(bf16x8*)&Ah[buf][row * BK + slot * 8] = hv;
            *(bf16x8*)&Al[buf][row * BK + slot * 8] = lv;
        }
#pragma unroll
        for (int p = 0; p < 2; ++p) {
            int id = tid + p * 256; int row = id >> 2; int slotl = id & 3;
            int slot = slotl ^ ((row >> 1) & 3);
            bf16x8 hv, lv;
#pragma unroll
            for (int j = 0; j < 4; ++j) {
                float f0 = br[2 * p][j];
                unsigned short h0 = f2bf(f0);
                hv[j] = (short)h0; lv[j] = (short)f2bf(f0 - bf2f(h0));
                float f1 = br[2 * p + 1][j];
                unsigned short h1 = f2bf(f1);
                hv[j + 4] = (short)h1; lv[j + 4] = (short)f2bf(f1 - bf2f(h1));
            }
            *(bf16x8*)&Bh[buf][row * BK + slot * 8] = hv;
            *(bf16x8*)&Bl[buf][row * BK + slot * 8] = lv;
        }
    };

    auto compute = [&](int buf) {
        bf16x8 ah[4], al[4];
#pragma unroll
        for (int m = 0; m < 4; ++m) {
            int row  = wv * 64 + m * 16 + (lane & 15);
            int slot = (lane >> 4) ^ ((row >> 1) & 3);
            ah[m] = *(const bf16x8*)&Ah[buf][row * BK + slot * 8];
            al[m] = *(const bf16x8*)&Al[buf][row * BK + slot * 8];
        }
#pragma unroll
        for (int n = 0; n < 8; ++n) {
            int row  = n * 16 + (lane & 15);
            int slot = (lane >> 4) ^ ((row >> 1) & 3);
            bf16x8 bh = *(const bf16x8*)&Bh[buf][row * BK + slot * 8];
            bf16x8 bl = *(const bf16x8*)&Bl[buf][row * BK + slot * 8];
#pragma unroll
            for (int m = 0; m < 4; ++m) {
                acc[m][n] = __builtin_amdgcn_mfma_f32_16x16x32_bf16(ah[m], bh, acc[m][n], 0, 0, 0);
                acc[m][n] = __builtin_amdgcn_mfma_f32_16x16x32_bf16(ah[m], bl, acc[m][n], 0, 0, 0);
                acc[m][n] = __builtin_amdgcn_mfma_f32_16x16x32_bf16(al[m], bh, acc[m][n], 0, 0, 0);
            }
        }
    };

    // prologue
    stage_load(0);
    stage_write(0);
    __syncthreads();

    for (int t = 0; t < NT; ++t) {
        const int cur = t & 1;
        const bool more = (t + 1 < NT);
        if (more) stage_load(t + 1);   // loads fly under the MFMAs (T14)
        compute(cur);
        if (more) stage_write(cur ^ 1);
        __syncthreads();               // one barrier per K-step (dbuf)
    }

    // epilogue: C/D layout col=lane&15, row=(lane>>4)*4+reg  [m89]
#pragma unroll
    for (int m = 0; m < 4; ++m) {
        int r0 = wv * 64 + m * 16 + (lane >> 4) * 4;
#pragma unroll
        for (int n = 0; n < 8; ++n) {
            int c = nc0 + n * 16 + (lane & 15);
#pragma unroll
            for (int r = 0; r < 4; ++r) {
                atomicAdd(&y[(size_t)(r0 + r) * OC + c], acc[m][n][r]);
            }
        }
    }
}

extern "C" void kernel_launch(void* const* d_in, const int* in_sizes, int n_in,
                              void* d_out, int out_size, void* d_ws, size_t ws_size,
                              hipStream_t stream) {
    const float* x  = (const float*)d_in[0];
    float*       w  = (float*)d_in[1];      // scattered in place (set = idempotent)
    const int*   fi = (const int*)d_in[2];
    const float* fv = (const float*)d_in[3];
    float*       y  = (float*)d_out;
    const int nflip = in_sizes[2];

    hipMemsetAsync(d_out, 0, (size_t)out_size * sizeof(float), stream);
    scatter_k<<<dim3((nflip + 1023) / 1024), dim3(256), 0, stream>>>(w, fi, fv, nflip);
    gemm_k<<<dim3(32 * KS), dim3(256), 0, stream>>>(x, w, y);
}